// Round 14
// baseline (158.210 us; speedup 1.0000x reference)
//
#include <hip/hip_runtime.h>
#include <math.h>

// Disable FP contraction file-wide so every rounding step is the one we wrote.
#pragma clang fp contract(off)

#define VOCAB 4096
#define NPTS  32768          // 4 * 8192
#define NELEM 98304          // NPTS * 3
#define BLOCK 256
#define GRID  2048           // 4 waves/block x 4 points/wave -> 32768 points

typedef float v2f __attribute__((ext_vector_type(2)));

static __device__ __forceinline__ v2f fma2(v2f a, v2f b, v2f c) {
#if __has_builtin(__builtin_elementwise_fma)
  return __builtin_elementwise_fma(a, b, c);    // llvm.fma.v2f32 -> v_pk_fma_f32
#else
  v2f r; r.x = fmaf(a.x, b.x, c.x); r.y = fmaf(a.y, b.y, c.y); return r;
#endif
}

// ---------------------------------------------------------------------------
// Kernel 0: pack codebook as float4 (-2e0, -2e1, -2e2, esq) and zero the
// counts/sums/sse workspace. Negation and x2 are exact; IEEE rounding is
// sign-symmetric, so an fma chain on these gives bit-exactly -2*dot of the
// reference chain (verified absmax 0, r10-r13). esq keeps the reference
// association (e0*e0 + e1*e1) + e2*e2.
// ---------------------------------------------------------------------------
__global__ __launch_bounds__(256) void vq_prep(
    const float* __restrict__ embed, float4* __restrict__ pc4,
    float* __restrict__ wz)
{
  const int c = blockIdx.x * 256 + threadIdx.x;   // [0, 4096)
  #pragma unroll
  for (int i = 0; i < 4; ++i) wz[4 * c + i] = 0.0f;   // counts+sums = 16384
  if (c == 0) wz[16384] = 0.0f;                       // sse

  float e0 = embed[3 * c + 0];
  float e1 = embed[3 * c + 1];
  float e2 = embed[3 * c + 2];
  float esq = (e0 * e0 + e1 * e1) + e2 * e2;
  pc4[c] = make_float4(-(e0 + e0), -(e1 + e1), -(e2 + e2), esq);
}

// ---------------------------------------------------------------------------
// Kernel 1: nearest-code assignment + quant_st + idx + scatter + SSE.
//
// r14 structure (GEMM-style register tile): each WAVE owns 4 points (point
// data broadcast into every lane's registers); the 64 LANES split the
// codebook 64-way. Iteration jb (0..15) covers 256 contiguous codes as 4
// sub-batches: code = 256*jb + 64*u + lane -- each load is a fully distinct,
// contiguous 1 KiB wave-load (no broadcast duplication: the r4-r12 40us wall
// was the 64x return-path waste of uniform reads; r13 removed it but had
// C=1 dependent-chain latency exposure). Here 4 independent loads per iter
// feed ~96 VALU ops (16 evals) -> loads hide under compute; no LDS, no
// barriers; ~20 waves/CU.
//
// Math: packed v2f chains on (-2e, esq) -- bit-identical per half to the
// reference (xsq - 2*dot) + esq (absmax-0 pedigree r10-r13). Tracking: per
// (u, point) stream with runtime jb; within a stream jb ascends and strict <
// keeps the first minimum; in-lane u-merge and the 6-hop 64-lane butterfly
// compare lexicographic (d, code-idx) => exact argmin first-min semantics.
// ---------------------------------------------------------------------------
__global__ __launch_bounds__(BLOCK, 4) void vq_assign(
    const float* __restrict__ feats, const float* __restrict__ embed,
    const float4* __restrict__ pc4,
    float* __restrict__ out_quant, float* __restrict__ out_idx,
    float* __restrict__ counts, float* __restrict__ sums,
    float* __restrict__ sse)
{
  const int tid  = threadIdx.x;
  const int lane = tid & 63;
  const int wv   = tid >> 6;
  const int wid  = blockIdx.x * 4 + wv;   // global wave id [0, 8192)
  const int pbase = wid * 4;              // 4 consecutive points per wave

  // Wave's 4 points (48 B, 16B-aligned, same addr across lanes -> broadcast).
  // p0=(v0.x,y,z) p1=(v0.w,v1.x,y) p2=(v1.z,w,v2.x) p3=(v2.y,z,w)
  const float4* fp = (const float4*)(feats + 3 * pbase);
  const float4 v0 = fp[0], v1 = fp[1], v2 = fp[2];

  // xsq per point, reference association (x0*x0 + x1*x1) + x2*x2.
  const float s0 = (v0.x * v0.x + v0.y * v0.y) + v0.z * v0.z;
  const float s1 = (v0.w * v0.w + v1.x * v1.x) + v1.y * v1.y;
  const float s2 = (v1.z * v1.z + v1.w * v1.w) + v2.x * v2.x;
  const float s3 = (v2.y * v2.y + v2.z * v2.z) + v2.w * v2.w;

  // packed point pairs {p0,p1} and {p2,p3}
  const v2f xa0 = {v0.x, v0.w}, xa1 = {v0.y, v1.x}, xa2 = {v0.z, v1.y};
  const v2f xb0 = {v1.z, v2.y}, xb1 = {v1.w, v2.z}, xb2 = {v2.x, v2.w};
  const v2f xqa = {s0, s1},     xqb = {s2, s3};

  // 16 streams: (u, point) -> (best d, winning jb). All indices compile-time
  // after unroll => registers (rule #20 safe).
  float bd[4][4];
  int   bj[4][4];
  #pragma unroll
  for (int u = 0; u < 4; ++u)
    #pragma unroll
    for (int p = 0; p < 4; ++p) { bd[u][p] = INFINITY; bj[u][p] = 0; }

  const float4* cp = pc4 + lane;          // lane's column of the code matrix

  #pragma unroll 4
  for (int jb = 0; jb < 16; ++jb) {
    #pragma unroll
    for (int u = 0; u < 4; ++u) {
      const float4 E = cp[256 * jb + 64 * u];   // contiguous 1 KiB wave-load
      const v2f e0 = {E.x, E.x}, e1 = {E.y, E.y}, e2 = {E.z, E.z};
      const v2f es = {E.w, E.w};

      v2f ta = xa0 * e0;                  // v_pk_mul_f32
      ta = fma2(xa1, e1, ta);             // v_pk_fma_f32
      ta = fma2(xa2, e2, ta);             // == -2*dot (bit-exact)
      ta = ta + xqa;                      // xsq - 2*dot
      ta = ta + es;                       // + esq (reference association)

      v2f tb = xb0 * e0;
      tb = fma2(xb1, e1, tb);
      tb = fma2(xb2, e2, tb);
      tb = tb + xqb;
      tb = tb + es;

      // strict <: first occurrence within the ascending-jb stream
      if (ta.x < bd[u][0]) { bd[u][0] = ta.x; bj[u][0] = jb; }
      if (ta.y < bd[u][1]) { bd[u][1] = ta.y; bj[u][1] = jb; }
      if (tb.x < bd[u][2]) { bd[u][2] = tb.x; bj[u][2] = jb; }
      if (tb.y < bd[u][3]) { bd[u][3] = tb.y; bj[u][3] = jb; }
    }
  }

  // In-lane merge of the 4 u-streams per point: lexicographic (d, code-idx).
  float fbd[4];
  int   fbi[4];
  #pragma unroll
  for (int p = 0; p < 4; ++p) {
    float b  = bd[0][p];
    int   bi = 256 * bj[0][p] + lane;           // u = 0
    #pragma unroll
    for (int u = 1; u < 4; ++u) {
      int cand = 256 * bj[u][p] + 64 * u + lane;
      if (bd[u][p] < b || (bd[u][p] == b && cand < bi)) { b = bd[u][p]; bi = cand; }
    }
    fbd[p] = b; fbi[p] = bi;
  }

  // 6-hop lexicographic (d, idx) butterfly across the full wave.
  #pragma unroll
  for (int m = 1; m <= 32; m <<= 1) {
    #pragma unroll
    for (int p = 0; p < 4; ++p) {
      float od = __shfl_xor(fbd[p], m, 64);
      int   oi = __shfl_xor(fbi[p], m, 64);
      if (od < fbd[p] || (od == fbd[p] && oi < fbi[p])) { fbd[p] = od; fbi[p] = oi; }
    }
  }

  // epilogue: lanes 0..3 each own one point (static selection, rule #20)
  float l = 0.0f;
  if (lane < 4) {
    int bidx = fbi[0];
    float x0 = v0.x, x1 = v0.y, x2 = v0.z;
    #pragma unroll
    for (int j = 1; j < 4; ++j) {
      if (lane == j) {
        bidx = fbi[j];
        x0 = (j == 1) ? v0.w : ((j == 2) ? v1.z : v2.y);
        x1 = (j == 1) ? v1.x : ((j == 2) ? v1.w : v2.z);
        x2 = (j == 1) ? v1.y : ((j == 2) ? v2.x : v2.w);
      }
    }
    const int p = pbase + lane;

    // winning code values straight from embed: bit-exact originals
    const float q0 = embed[3 * bidx + 0];
    const float q1 = embed[3 * bidx + 1];
    const float q2 = embed[3 * bidx + 2];

    // quant_st = feats + (quant - feats), exactly as the reference does
    out_quant[3 * p + 0] = x0 + (q0 - x0);
    out_quant[3 * p + 1] = x1 + (q1 - x1);
    out_quant[3 * p + 2] = x2 + (q2 - x2);
    out_idx[p] = (float)bidx;

    atomicAdd(&counts[bidx], 1.0f);
    atomicAdd(&sums[3 * bidx + 0], x0);
    atomicAdd(&sums[3 * bidx + 1], x1);
    atomicAdd(&sums[3 * bidx + 2], x2);

    float d0 = q0 - x0, d1 = q1 - x1, d2 = q2 - x2;
    l = (d0 * d0 + d1 * d1) + d2 * d2;
  }

  // wave-reduce SSE partials (4 contributing lanes), 1 atomic per wave
  #pragma unroll
  for (int m = 1; m <= 32; m <<= 1) l += __shfl_xor(l, m, 64);
  if (lane == 0) atomicAdd(sse, l);
}

// ---------------------------------------------------------------------------
// Kernel 2: EMA update, global n-reduction, normalized embed, loss finalize.
// (unchanged from the verified rounds)
// ---------------------------------------------------------------------------
__global__ __launch_bounds__(1024) void vq_ema(
    const float* __restrict__ counts, const float* __restrict__ sums,
    const float* __restrict__ sse,
    const float* __restrict__ ema_cs, const float* __restrict__ ema_w,
    float* __restrict__ out_loss, float* __restrict__ out_ncs,
    float* __restrict__ out_nw, float* __restrict__ out_nemb)
{
  __shared__ float part[16];
  const int tid = threadIdx.x;
  const float DEC = 0.99f;
  const float OMD = (float)(1.0 - 0.99);
  const float EPS = 1e-5f;

  float ncs[4];
  float nw[12];
  float nsum = 0.0f;

  #pragma unroll
  for (int k = 0; k < 4; ++k) {
    int v = k * 1024 + tid;
    float t = DEC * ema_cs[v] + OMD * counts[v];
    ncs[k] = t;
    out_ncs[v] = t;
    nsum += t;
    #pragma unroll
    for (int d = 0; d < 3; ++d) {
      float w = DEC * ema_w[3 * v + d] + OMD * sums[3 * v + d];
      nw[3 * k + d] = w;
      out_nw[3 * v + d] = w;
    }
  }

  #pragma unroll
  for (int m = 1; m <= 32; m <<= 1) nsum += __shfl_xor(nsum, m, 64);
  if ((tid & 63) == 0) part[tid >> 6] = nsum;
  __syncthreads();

  float n = 0.0f;
  #pragma unroll
  for (int i = 0; i < 16; ++i) n += part[i];
  const float denom = n + (float)VOCAB * EPS;

  #pragma unroll
  for (int k = 0; k < 4; ++k) {
    int v = k * 1024 + tid;
    float cs = (ncs[k] + EPS) / denom * n;
    #pragma unroll
    for (int d = 0; d < 3; ++d)
      out_nemb[3 * v + d] = nw[3 * k + d] / cs;
  }

  if (tid == 0) {
    float m = sse[0] / (float)NELEM;
    out_loss[0] = m + 0.25f * m;   // mean((q-f)^2) + 0.25*mean((f-q)^2)
  }
}

// ---------------------------------------------------------------------------
extern "C" void kernel_launch(void* const* d_in, const int* in_sizes, int n_in,
                              void* d_out, int out_size, void* d_ws, size_t ws_size,
                              hipStream_t stream) {
  const float* feats  = (const float*)d_in[0];   // (4,8192,3)
  const float* embed  = (const float*)d_in[1];   // (4096,3)
  const float* ema_cs = (const float*)d_in[2];   // (4096,)
  const float* ema_w  = (const float*)d_in[3];   // (4096,3)

  float* out      = (float*)d_out;
  float* o_quant  = out;                       // 98304
  float* o_idx    = out + 98304;               // 32768
  float* o_loss   = out + 131072;              // 1
  float* o_ncs    = out + 131073;              // 4096
  float* o_nw     = out + 135169;              // 12288
  float* o_nemb   = out + 147457;              // 12288

  float*  ws_f      = (float*)d_ws;
  float*  ws_counts = ws_f;                    // 4096
  float*  ws_sums   = ws_f + 4096;             // 12288
  float*  ws_sse    = ws_f + 16384;            // 1 (+3 pad)
  float4* ws_pc4    = (float4*)(ws_f + 16388); // 4096 float4 (byte 65552, 16B-aligned)

  vq_prep<<<VOCAB / 256, 256, 0, stream>>>(embed, ws_pc4, ws_f);

  vq_assign<<<GRID, BLOCK, 0, stream>>>(
      feats, embed, ws_pc4, o_quant, o_idx, ws_counts, ws_sums, ws_sse);

  vq_ema<<<1, 1024, 0, stream>>>(
      ws_counts, ws_sums, ws_sse, ema_cs, ema_w,
      o_loss, o_ncs, o_nw, o_nemb);
}

// Round 15
// 130.012 us; speedup vs baseline: 1.2169x; 1.2169x over previous
//
#include <hip/hip_runtime.h>
#include <math.h>

// Disable FP contraction file-wide so every rounding step is the one we wrote.
#pragma clang fp contract(off)

#define VOCAB 4096
#define NPTS  32768          // 4 * 8192
#define NELEM 98304          // NPTS * 3
#define BLOCK 1024
#define GRID  512            // 16 waves/block x 4 pts/wave -> 64 pts/block

typedef float v2f __attribute__((ext_vector_type(2)));

static __device__ __forceinline__ v2f fma2(v2f a, v2f b, v2f c) {
#if __has_builtin(__builtin_elementwise_fma)
  return __builtin_elementwise_fma(a, b, c);    // llvm.fma.v2f32 -> v_pk_fma_f32
#else
  v2f r; r.x = fmaf(a.x, b.x, c.x); r.y = fmaf(a.y, b.y, c.y); return r;
#endif
}

// ---------------------------------------------------------------------------
// Kernel 0: pack codebook as float4 (-2e0, -2e1, -2e2, esq) and zero the
// counts/sums/sse workspace. Negation and x2 are exact; IEEE rounding is
// sign-symmetric, so an fma chain on these gives bit-exactly -2*dot of the
// reference chain (verified absmax 0, r10-r14). esq keeps the reference
// association (e0*e0 + e1*e1) + e2*e2.
// ---------------------------------------------------------------------------
__global__ __launch_bounds__(256) void vq_prep(
    const float* __restrict__ embed, float4* __restrict__ pc4,
    float* __restrict__ wz)
{
  const int c = blockIdx.x * 256 + threadIdx.x;   // [0, 4096)
  #pragma unroll
  for (int i = 0; i < 4; ++i) wz[4 * c + i] = 0.0f;   // counts+sums = 16384
  if (c == 0) wz[16384] = 0.0f;                       // sse

  float e0 = embed[3 * c + 0];
  float e1 = embed[3 * c + 1];
  float e2 = embed[3 * c + 2];
  float esq = (e0 * e0 + e1 * e1) + e2 * e2;
  pc4[c] = make_float4(-(e0 + e0), -(e1 + e1), -(e2 + e2), esq);
}

// ---------------------------------------------------------------------------
// Kernel 1: nearest-code assignment + quant_st + idx + scatter + SSE.
//
// r15 = the combination 14 rounds of evidence point at:
//  - codebook in LDS (r13/r14 showed global streams lose: L1 thrash +
//    exposed latency), shared by all 32 waves/CU;
//  - PER-LANE-DISTINCT ds_reads (r4-r12 showed broadcast reads waste 64x
//    of the LDS return path -- the 40us wall): lane reads code ci = 64k+lane
//    at addr lane*16 + 1024k (one addr VGPR + 16-bit imm offsets <= 64512,
//    conflict-free ~12cyc case) -- ONE ds_read feeds the whole wave 64 codes;
//  - wave owns 4 points broadcast in registers (r14-verified math+epilogue):
//    each lane evaluates its code against all 4 points.
// Per-CU budget: 2048 ds_reads x 12cyc = 10.2us port; VALU ~22 instr/iter
// x 64 x 8 waves/SIMD x 2cyc = 9.4us issue; independent loads 4-deep at
// unroll-4 hide under 44cyc compute/load. Grid 512 = exactly 2 blocks/CU
// (128 KiB LDS), 32 waves/CU; launch_bounds caps VGPR at 64 (est ~48).
//
// Math: packed v2f chains on (-2e, esq) -- bit-identical per half to the
// reference (xsq - 2*dot) + esq (absmax-0 pedigree r10-r14). Tie-break:
// lane stream ascends in k, strict < keeps first min; in-lane and cross-lane
// merges compare lexicographic (d, code-idx) => exact argmin semantics.
// ---------------------------------------------------------------------------
__global__ __launch_bounds__(BLOCK, 8) void vq_assign(
    const float* __restrict__ feats, const float* __restrict__ embed,
    const float4* __restrict__ pc4,
    float* __restrict__ out_quant, float* __restrict__ out_idx,
    float* __restrict__ counts, float* __restrict__ sums,
    float* __restrict__ sse)
{
  extern __shared__ float4 lpc[];          // [VOCAB] = 64 KiB dynamic

  const int tid  = threadIdx.x;
  const int lane = tid & 63;
  const int wv   = tid >> 6;
  const int wid  = blockIdx.x * 16 + wv;   // global wave id [0, 8192)
  const int pbase = wid * 4;               // 4 consecutive points per wave

  // Stage packed codebook into LDS (coalesced float4 copies, 4 per thread).
  #pragma unroll
  for (int c = tid; c < VOCAB; c += BLOCK) lpc[c] = pc4[c];
  __syncthreads();

  // Wave's 4 points (48 B, same addr across lanes -> broadcast loads).
  // p0=(v0.x,y,z) p1=(v0.w,v1.x,y) p2=(v1.z,w,v2.x) p3=(v2.y,z,w)
  const float4* fp = (const float4*)(feats + 3 * pbase);
  const float4 v0 = fp[0], v1 = fp[1], v2 = fp[2];

  // xsq per point, reference association (x0*x0 + x1*x1) + x2*x2.
  const float s0 = (v0.x * v0.x + v0.y * v0.y) + v0.z * v0.z;
  const float s1 = (v0.w * v0.w + v1.x * v1.x) + v1.y * v1.y;
  const float s2 = (v1.z * v1.z + v1.w * v1.w) + v2.x * v2.x;
  const float s3 = (v2.y * v2.y + v2.z * v2.z) + v2.w * v2.w;

  // packed point pairs {p0,p1} and {p2,p3}
  const v2f xa0 = {v0.x, v0.w}, xa1 = {v0.y, v1.x}, xa2 = {v0.z, v1.y};
  const v2f xb0 = {v1.z, v2.y}, xb1 = {v1.w, v2.z}, xb2 = {v2.x, v2.w};
  const v2f xqa = {s0, s1},     xqb = {s2, s3};

  // 4 per-point streams: (best d, winning k). Compile-time indices only.
  float bd[4] = {INFINITY, INFINITY, INFINITY, INFINITY};
  int   bk[4] = {0, 0, 0, 0};

  const float4* lanep = lpc + lane;        // lane's code column in LDS

  #pragma unroll 4
  for (int k = 0; k < VOCAB / 64; ++k) {
    const float4 E = lanep[64 * k];        // ds_read_b128, offset:1024k
    const v2f e0 = {E.x, E.x}, e1 = {E.y, E.y}, e2 = {E.z, E.z};
    const v2f es = {E.w, E.w};

    v2f ta = xa0 * e0;                     // v_pk_mul_f32
    ta = fma2(xa1, e1, ta);                // v_pk_fma_f32
    ta = fma2(xa2, e2, ta);                // == -2*dot (bit-exact)
    ta = ta + xqa;                         // xsq - 2*dot
    ta = ta + es;                          // + esq (reference association)

    v2f tb = xb0 * e0;
    tb = fma2(xb1, e1, tb);
    tb = fma2(xb2, e2, tb);
    tb = tb + xqb;
    tb = tb + es;

    // strict <: first occurrence within the ascending-k stream
    if (ta.x < bd[0]) { bd[0] = ta.x; bk[0] = k; }
    if (ta.y < bd[1]) { bd[1] = ta.y; bk[1] = k; }
    if (tb.x < bd[2]) { bd[2] = tb.x; bk[2] = k; }
    if (tb.y < bd[3]) { bd[3] = tb.y; bk[3] = k; }
  }

  // per-lane code index, then 6-hop lexicographic (d, idx) wave butterfly
  float fbd[4];
  int   fbi[4];
  #pragma unroll
  for (int p = 0; p < 4; ++p) { fbd[p] = bd[p]; fbi[p] = 64 * bk[p] + lane; }
  #pragma unroll
  for (int m = 1; m <= 32; m <<= 1) {
    #pragma unroll
    for (int p = 0; p < 4; ++p) {
      float od = __shfl_xor(fbd[p], m, 64);
      int   oi = __shfl_xor(fbi[p], m, 64);
      if (od < fbd[p] || (od == fbd[p] && oi < fbi[p])) { fbd[p] = od; fbi[p] = oi; }
    }
  }

  // epilogue: lanes 0..3 each own one point (static selection; r14-verified)
  float l = 0.0f;
  if (lane < 4) {
    int bidx = fbi[0];
    float x0 = v0.x, x1 = v0.y, x2 = v0.z;
    #pragma unroll
    for (int j = 1; j < 4; ++j) {
      if (lane == j) {
        bidx = fbi[j];
        x0 = (j == 1) ? v0.w : ((j == 2) ? v1.z : v2.y);
        x1 = (j == 1) ? v1.x : ((j == 2) ? v1.w : v2.z);
        x2 = (j == 1) ? v1.y : ((j == 2) ? v2.x : v2.w);
      }
    }
    const int p = pbase + lane;

    // winning code values straight from embed: bit-exact originals
    const float q0 = embed[3 * bidx + 0];
    const float q1 = embed[3 * bidx + 1];
    const float q2 = embed[3 * bidx + 2];

    // quant_st = feats + (quant - feats), exactly as the reference does
    out_quant[3 * p + 0] = x0 + (q0 - x0);
    out_quant[3 * p + 1] = x1 + (q1 - x1);
    out_quant[3 * p + 2] = x2 + (q2 - x2);
    out_idx[p] = (float)bidx;

    atomicAdd(&counts[bidx], 1.0f);
    atomicAdd(&sums[3 * bidx + 0], x0);
    atomicAdd(&sums[3 * bidx + 1], x1);
    atomicAdd(&sums[3 * bidx + 2], x2);

    float d0 = q0 - x0, d1 = q1 - x1, d2 = q2 - x2;
    l = (d0 * d0 + d1 * d1) + d2 * d2;
  }

  // wave-reduce SSE partials (4 contributing lanes), 1 atomic per wave
  #pragma unroll
  for (int m = 1; m <= 32; m <<= 1) l += __shfl_xor(l, m, 64);
  if (lane == 0) atomicAdd(sse, l);
}

// ---------------------------------------------------------------------------
// Kernel 2: EMA update, global n-reduction, normalized embed, loss finalize.
// (unchanged from the verified rounds)
// ---------------------------------------------------------------------------
__global__ __launch_bounds__(1024) void vq_ema(
    const float* __restrict__ counts, const float* __restrict__ sums,
    const float* __restrict__ sse,
    const float* __restrict__ ema_cs, const float* __restrict__ ema_w,
    float* __restrict__ out_loss, float* __restrict__ out_ncs,
    float* __restrict__ out_nw, float* __restrict__ out_nemb)
{
  __shared__ float part[16];
  const int tid = threadIdx.x;
  const float DEC = 0.99f;
  const float OMD = (float)(1.0 - 0.99);
  const float EPS = 1e-5f;

  float ncs[4];
  float nw[12];
  float nsum = 0.0f;

  #pragma unroll
  for (int k = 0; k < 4; ++k) {
    int v = k * 1024 + tid;
    float t = DEC * ema_cs[v] + OMD * counts[v];
    ncs[k] = t;
    out_ncs[v] = t;
    nsum += t;
    #pragma unroll
    for (int d = 0; d < 3; ++d) {
      float w = DEC * ema_w[3 * v + d] + OMD * sums[3 * v + d];
      nw[3 * k + d] = w;
      out_nw[3 * v + d] = w;
    }
  }

  #pragma unroll
  for (int m = 1; m <= 32; m <<= 1) nsum += __shfl_xor(nsum, m, 64);
  if ((tid & 63) == 0) part[tid >> 6] = nsum;
  __syncthreads();

  float n = 0.0f;
  #pragma unroll
  for (int i = 0; i < 16; ++i) n += part[i];
  const float denom = n + (float)VOCAB * EPS;

  #pragma unroll
  for (int k = 0; k < 4; ++k) {
    int v = k * 1024 + tid;
    float cs = (ncs[k] + EPS) / denom * n;
    #pragma unroll
    for (int d = 0; d < 3; ++d)
      out_nemb[3 * v + d] = nw[3 * k + d] / cs;
  }

  if (tid == 0) {
    float m = sse[0] / (float)NELEM;
    out_loss[0] = m + 0.25f * m;   // mean((q-f)^2) + 0.25*mean((f-q)^2)
  }
}

// ---------------------------------------------------------------------------
extern "C" void kernel_launch(void* const* d_in, const int* in_sizes, int n_in,
                              void* d_out, int out_size, void* d_ws, size_t ws_size,
                              hipStream_t stream) {
  const float* feats  = (const float*)d_in[0];   // (4,8192,3)
  const float* embed  = (const float*)d_in[1];   // (4096,3)
  const float* ema_cs = (const float*)d_in[2];   // (4096,)
  const float* ema_w  = (const float*)d_in[3];   // (4096,3)

  float* out      = (float*)d_out;
  float* o_quant  = out;                       // 98304
  float* o_idx    = out + 98304;               // 32768
  float* o_loss   = out + 131072;              // 1
  float* o_ncs    = out + 131073;              // 4096
  float* o_nw     = out + 135169;              // 12288
  float* o_nemb   = out + 147457;              // 12288

  float*  ws_f      = (float*)d_ws;
  float*  ws_counts = ws_f;                    // 4096
  float*  ws_sums   = ws_f + 4096;             // 12288
  float*  ws_sse    = ws_f + 16384;            // 1 (+3 pad)
  float4* ws_pc4    = (float4*)(ws_f + 16388); // 4096 float4 (byte 65552, 16B-aligned)

  vq_prep<<<VOCAB / 256, 256, 0, stream>>>(embed, ws_pc4, ws_f);

  vq_assign<<<GRID, BLOCK, VOCAB * sizeof(float4), stream>>>(
      feats, embed, ws_pc4, o_quant, o_idx, ws_counts, ws_sums, ws_sse);

  vq_ema<<<1, 1024, 0, stream>>>(
      ws_counts, ws_sums, ws_sse, ema_cs, ema_w,
      o_loss, o_ncs, o_nw, o_nemb);
}